// Round 2
// baseline (193.080 us; speedup 1.0000x reference)
//
#include <hip/hip_runtime.h>
#include <hip/hip_bf16.h>

// GDGCN: out[b,c,m,t] = sum_n softmax_row(relu(t1 nv2^T))[n,m] * x[b,c,n,t]
// t1 = nv1 @ (sum_d tv[d] k[d,:,:]);  N=8192, D=32, cols = B*C*T = 192.
// R13: barrier-free k_mega, builtins-only (R12's inline-asm K16 MFMA gave
// NaN -- hazard recognizer doesn't see INLINEASM MFMAs). Row-permutation
// trick: gen A-frag loads t1 rows permuted n_g(row)=8*(row>>2)+(row&3)
// (+4 for phase B). Gen 16x16x32 output then holds E[nt+8q+r][m] (phase A)
// and E[nt+8q+4+r][m] (phase B) per lane -- concatenated {A.r0..3,B.r0..3}
// IS the bf16x8 B-frag (k=q*8+e) of the proven 16x16x32 MFMA. Each wave
// self-generates the full 64-m E tile per 32-n slice and accumulates its
// own 3 col-tiles: no LDS, no __syncthreads, no cross-wave traffic.
// Gen/exp2 4x redundant per block (accepted: replaces the 71.6us
// barrier-bound exchange). k_y/k_reduce LDS padded 12->13 (bank conflicts).

#define NN 8192
#define DD 32
#define TT 12
#define NSPLIT 8
#define CHUNK 1024

typedef __attribute__((ext_vector_type(8))) short bf16x8;
typedef __attribute__((ext_vector_type(4))) float f32x4;

static __device__ __forceinline__ unsigned short f2bf(float f) {
  unsigned int u = __float_as_uint(f);
  u = (u + 0x7FFFu + ((u >> 16) & 1u)) >> 16;  // RNE bf16
  return (unsigned short)u;
}

static __device__ __forceinline__ float fexp2(float x) {
#if __has_builtin(__builtin_amdgcn_exp2f)
  return __builtin_amdgcn_exp2f(x);
#else
  return __builtin_exp2f(x);
#endif
}

#define MFMA32(A, B, C) __builtin_amdgcn_mfma_f32_16x16x32_bf16((A), (B), (C), 0, 0, 0)

// ---- fused: core = tv.k ; t1 = (nv1@core)*log2e (bf16) ; nv2 -> bf16 ; sums=0
__global__ __launch_bounds__(256) void k_prep(const float* __restrict__ nv1,
                                              const float* __restrict__ nv2,
                                              const float* __restrict__ timevec,
                                              const float* __restrict__ kk,
                                              const int* __restrict__ tind,
                                              unsigned short* __restrict__ t1b,
                                              unsigned short* __restrict__ nv2b,
                                              float* __restrict__ sums) {
  __shared__ float cs[1024];
  const int tid = threadIdx.x;
  if (tid < 128) sums[blockIdx.x * 128 + tid] = 0.f;
  const float* tv = timevec + (size_t)tind[0] * DD;
  for (int idx = tid; idx < 1024; idx += 256) {
    float acc = 0.f;
#pragma unroll
    for (int d = 0; d < DD; ++d) acc += tv[d] * kk[d * 1024 + idx];
    cs[idx] = acc;
  }
  __syncthreads();
  const int nbase = blockIdx.x * 128;
  const int f = tid & 31, sub = tid >> 5;
#pragma unroll 4
  for (int it = 0; it < 16; ++it) {
    const int n = nbase + it * 8 + sub;
    const float* nr = nv1 + (size_t)n * DD;
    float acc = 0.f;
#pragma unroll
    for (int e = 0; e < DD; ++e) acc += nr[e] * cs[e * DD + f];
    t1b[(size_t)n * DD + f] = f2bf(acc * 1.4426950408889634f);  // fold log2(e)
  }
#pragma unroll 4
  for (int it = 0; it < 16; ++it) {
    const int idx = nbase * DD + it * 256 + tid;
    nv2b[idx] = f2bf(nv2[idx]);
  }
}

// ---- sums[n] += sum_m exp2(relu(t1[n].nv2[m]))  grid (128 n, 8 m-chunks) ----
__global__ __launch_bounds__(256) void k_stats(const unsigned short* __restrict__ t1b,
                                               const unsigned short* __restrict__ nv2b,
                                               float* __restrict__ sums) {
  const int tid = threadIdx.x;
  const int w = tid >> 6, lane = tid & 63, q = lane >> 4, i16 = lane & 15;
  const int nbase = blockIdx.x * 64 + w * 16;
  bf16x8 a = *(const bf16x8*)(t1b + (size_t)(nbase + i16) * DD + q * 8);
  const f32x4 z4 = {0.f, 0.f, 0.f, 0.f};
  float s[4] = {0.f, 0.f, 0.f, 0.f};
  const int m0 = blockIdx.y * 1024;
  for (int mt = m0; mt < m0 + 1024; mt += 64) {
#pragma unroll
    for (int u = 0; u < 4; ++u) {
      bf16x8 b = *(const bf16x8*)(nv2b + (size_t)(mt + u * 16 + i16) * DD + q * 8);
      f32x4 d = __builtin_amdgcn_mfma_f32_16x16x32_bf16(a, b, z4, 0, 0, 0);
#pragma unroll
      for (int r = 0; r < 4; ++r) s[r] += fexp2(fmaxf(d[r], 0.f));
    }
  }
#pragma unroll
  for (int r = 0; r < 4; ++r)
    for (int off = 1; off < 16; off <<= 1) s[r] += __shfl_xor(s[r], off, 64);
  if (i16 == 0) {
#pragma unroll
    for (int r = 0; r < 4; ++r) atomicAdd(&sums[nbase + q * 4 + r], s[r]);
  }
}

// ---- yT[col][n] = bf16(x[bc][n][t] / sums[n]) via LDS transpose (pad 12->13) ----
__global__ __launch_bounds__(256) void k_y(const float* __restrict__ x,
                                           const float* __restrict__ sums,
                                           unsigned short* __restrict__ yT) {
  __shared__ float xs[3328];  // 256 * 13
  const int tid = threadIdx.x;
  const int n0 = blockIdx.x * 256;
  const int bc = blockIdx.y;
  const float* xp = x + (size_t)bc * NN * TT + (size_t)n0 * TT;
#pragma unroll
  for (int j = 0; j < 12; ++j) {
    const int idx = j * 256 + tid;
    xs[(idx / 12) * 13 + idx % 12] = xp[idx];
  }
  __syncthreads();
  const float rinv = 1.0f / sums[n0 + tid];
#pragma unroll
  for (int t = 0; t < 12; ++t)
    yT[(size_t)(bc * TT + t) * NN + n0 + tid] = f2bf(xs[tid * 13 + t] * rinv);
}

// ---- k_mega: part[nc][col][m] = sum_{n in chunk} E[n][m] * y[col][n] ----
// grid (128 m-blocks of 64, 8 chunks of 1024 n); 256 thr = 4 waves.
// Barrier-free: wave w owns col-tiles [w*3, w*3+3) and ALL 1024 n. Per
// 32-n slice: gen E logits (2 phases x 4 m-strips, 16x16x32, t1 rows
// permuted) -> relu/exp2/f2bf in regs -> concat phases into bf16x8 B-frag
// -> 12x 16x16x32 acc. Builtins only; no LDS, no __syncthreads.
__global__ __launch_bounds__(256) void k_mega(const unsigned short* __restrict__ t1b,
                                              const unsigned short* __restrict__ nv2b,
                                              const unsigned short* __restrict__ yT,
                                              float* __restrict__ part) {
  const int tid = threadIdx.x;
  const int w = tid >> 6, lane = tid & 63, q = lane >> 4, i16 = lane & 15;
  const int mb = blockIdx.x * 64;
  const int nt0 = blockIdx.y * CHUNK;

  // gen B-frags (loop-invariant): bg[ms][k=d] at col m = mb+ms*16+i16
  bf16x8 bg[4];
#pragma unroll
  for (int ms = 0; ms < 4; ++ms)
    bg[ms] = *(const bf16x8*)(nv2b + (size_t)(mb + ms * 16 + i16) * DD + q * 8);

  f32x4 acc[3][4];
#pragma unroll
  for (int c = 0; c < 3; ++c)
#pragma unroll
    for (int ms = 0; ms < 4; ++ms) acc[c][ms] = (f32x4){0.f, 0.f, 0.f, 0.f};

  // gen A-frag row permutation: A-row i16 <- t1 row nt + 8*(i16>>2)+(i16&3)
  // (+4 for phase B). Then gen D at lane (q,i16), phase A holds
  // E[nt+8q+r][m], phase B holds E[nt+8q+4+r][m] -> concat = K=32 B-frag.
  const int perm = ((i16 >> 2) << 3) | (i16 & 3);
  const unsigned short* tp = t1b + (size_t)(nt0 + perm) * DD + q * 8;
  // acc A-frags: y[col = (w*3+c)*16 + i16][n = nt + q*8 + e]
  const unsigned short* yp0 = yT + (size_t)((w * 3 + 0) * 16 + i16) * NN + nt0 + q * 8;
  const unsigned short* yp1 = yp0 + (size_t)16 * NN;
  const unsigned short* yp2 = yp1 + (size_t)16 * NN;

  bf16x8 alo = *(const bf16x8*)tp;
  bf16x8 ahi = *(const bf16x8*)(tp + 4 * DD);
  bf16x8 y0 = *(const bf16x8*)yp0;
  bf16x8 y1 = *(const bf16x8*)yp1;
  bf16x8 y2 = *(const bf16x8*)yp2;

  const f32x4 z4 = {0.f, 0.f, 0.f, 0.f};

  for (int sl = 0; sl < 32; ++sl) {
    // prefetch next-slice operands (hides L1/L2 latency under gen+acc)
    bf16x8 alo_n, ahi_n, y0n, y1n, y2n;
    if (sl < 31) {
      const int o = (sl + 1) * 32;
      alo_n = *(const bf16x8*)(tp + o * DD);
      ahi_n = *(const bf16x8*)(tp + o * DD + 4 * DD);
      y0n = *(const bf16x8*)(yp0 + o);
      y1n = *(const bf16x8*)(yp1 + o);
      y2n = *(const bf16x8*)(yp2 + o);
    } else {
      alo_n = alo; ahi_n = ahi; y0n = y0; y1n = y1; y2n = y2;
    }

    // gen + pack: e[ms] = bf16x8 B-frag of E for this 32-n slice
    bf16x8 e[4];
#pragma unroll
    for (int ms = 0; ms < 4; ++ms) {
      f32x4 dlo = MFMA32(alo, bg[ms], z4);
      f32x4 dhi = MFMA32(ahi, bg[ms], z4);
      bf16x8 t;
#pragma unroll
      for (int r = 0; r < 4; ++r) {
        t[r] = (short)f2bf(fexp2(fmaxf(dlo[r], 0.f)));
        t[4 + r] = (short)f2bf(fexp2(fmaxf(dhi[r], 0.f)));
      }
      e[ms] = t;
    }

    // acc: D[ycol][m] += y(16 cols x 32 n) * E(32 n x 16 m)
#pragma unroll
    for (int ms = 0; ms < 4; ++ms) {
      acc[0][ms] = MFMA32(y0, e[ms], acc[0][ms]);
      acc[1][ms] = MFMA32(y1, e[ms], acc[1][ms]);
      acc[2][ms] = MFMA32(y2, e[ms], acc[2][ms]);
    }

    alo = alo_n; ahi = ahi_n; y0 = y0n; y1 = y1n; y2 = y2n;
  }

  // epilogue: lane holds col = (w*3+c)*16 + q*4 + r, m = mb + ms*16 + i16
  float* pp = part + (size_t)blockIdx.y * 192 * NN;
#pragma unroll
  for (int c = 0; c < 3; ++c)
#pragma unroll
    for (int ms = 0; ms < 4; ++ms) {
      const int colbase = (w * 3 + c) * 16 + q * 4;
      const int m = mb + ms * 16 + i16;
#pragma unroll
      for (int r = 0; r < 4; ++r)
        pp[(size_t)(colbase + r) * NN + m] = acc[c][ms][r];
    }
}

// ---- reduce NSPLIT partials + transpose to out[bc][m][t] (pad 12->13) ----
__global__ __launch_bounds__(256) void k_reduce(const float* __restrict__ part,
                                                float* __restrict__ out) {
  __shared__ float os[3328];  // 256 * 13
  const int tid = threadIdx.x;
  const int m0 = blockIdx.x * 256;
  const int bc = blockIdx.y;
#pragma unroll
  for (int t = 0; t < 12; ++t) {
    const int col = bc * TT + t;
    float s = 0.f;
#pragma unroll
    for (int nc = 0; nc < NSPLIT; ++nc)
      s += part[((size_t)nc * 192 + col) * NN + m0 + tid];
    os[tid * 13 + t] = s;
  }
  __syncthreads();
  float* op = out + (size_t)bc * NN * TT + (size_t)m0 * TT;
#pragma unroll
  for (int j = 0; j < 12; ++j) {
    const int idx = j * 256 + tid;
    op[idx] = os[(idx / 12) * 13 + idx % 12];
  }
}

extern "C" void kernel_launch(void* const* d_in, const int* in_sizes, int n_in,
                              void* d_out, int out_size, void* d_ws, size_t ws_size,
                              hipStream_t stream) {
  const float* x = (const float*)d_in[0];
  const float* nv1 = (const float*)d_in[1];
  const float* nv2 = (const float*)d_in[2];
  const float* tv = (const float*)d_in[3];
  const float* kk = (const float*)d_in[4];
  const int* tind = (const int*)d_in[5];
  float* out = (float*)d_out;

  char* ws = (char*)d_ws;
  unsigned short* t1b  = (unsigned short*)(ws);            //  524288 B
  unsigned short* nv2b = (unsigned short*)(ws + 524288);   //  524288 B
  float* sums          = (float*)(ws + 1048576);           //   32768 B
  unsigned short* yT   = (unsigned short*)(ws + 1081344);  // 3145728 B -> 4227072
  float* part          = (float*)(ws + 4227072);           // 50331648 B -> 54558720

  k_prep<<<64, 256, 0, stream>>>(nv1, nv2, tv, kk, tind, t1b, nv2b, sums);
  k_stats<<<dim3(128, 8), 256, 0, stream>>>(t1b, nv2b, sums);
  k_y<<<dim3(32, 16), 256, 0, stream>>>(x, sums, yT);
  k_mega<<<dim3(128, NSPLIT), 256, 0, stream>>>(t1b, nv2b, yT, part);
  k_reduce<<<dim3(32, 16), 256, 0, stream>>>(part, out);
}

// Round 4
// 184.315 us; speedup vs baseline: 1.0476x; 1.0476x over previous
//
#include <hip/hip_runtime.h>
#include <hip/hip_bf16.h>

// GDGCN: out[b,c,m,t] = sum_n softmax_row(relu(t1 nv2^T))[n,m] * x[b,c,n,t]
// t1 = nv1 @ (sum_d tv[d] k[d,:,:]);  N=8192, D=32, cols = B*C*T = 192.
// R15: R14's pipelined barrier-free k_mega with the E-pack reverted to
// bit-exact RNE (R13-proven). R14's v_cvt_pk_bf16_f32 is NOT
// round-to-nearest-even on gfx950 (absmax 0.080 vs 0.027 threshold;
// truncation bias) -- pk_rne below reproduces f2bf's rounding exactly,
// pairwise (lshr + and_or combine).
// Structure (HW-verified R13): gen A-frag loads t1 rows permuted
// n_g(row)=8*(row>>2)+(row&3), +4 for phase B; gen 16x16x32 output concat
// {A.r0..3,B.r0..3} IS the bf16x8 B-frag of the acc 16x16x32 MFMA.
// Pipeline (R14): acc MFMAs of slice sl-1 cover gen->exp2->pack of slice
// sl; grouped 2+2 m-strips bound the f32x4 transient at 16 VGPRs.
// __launch_bounds__(256,3) caps regs ~168 -> 3 waves/SIMD (R13 hit a
// 2-wave AGPR cliff, Occupancy 24%). No LDS, no __syncthreads.

#define NN 8192
#define DD 32
#define TT 12
#define NSPLIT 8
#define CHUNK 1024

typedef __attribute__((ext_vector_type(8))) short bf16x8;
typedef __attribute__((ext_vector_type(4))) float f32x4;
typedef __attribute__((ext_vector_type(4))) unsigned int u32x4;

static __device__ __forceinline__ unsigned short f2bf(float f) {
  unsigned int u = __float_as_uint(f);
  u = (u + 0x7FFFu + ((u >> 16) & 1u)) >> 16;  // RNE bf16
  return (unsigned short)u;
}

static __device__ __forceinline__ float fexp2(float x) {
#if __has_builtin(__builtin_amdgcn_exp2f)
  return __builtin_amdgcn_exp2f(x);
#else
  return __builtin_exp2f(x);
#endif
}

#define MFMA32(A, B, C) __builtin_amdgcn_mfma_f32_16x16x32_bf16((A), (B), (C), 0, 0, 0)

// pack two f32 -> one u32 of 2x bf16, RNE, bit-identical to f2bf pairs
static __device__ __forceinline__ unsigned int pk_rne(float a, float b) {
  unsigned int ua = __float_as_uint(a);
  unsigned int ub = __float_as_uint(b);
  ua = ua + 0x7FFFu + ((ua >> 16) & 1u);
  ub = ub + 0x7FFFu + ((ub >> 16) & 1u);
  return (ua >> 16) | (ub & 0xFFFF0000u);  // v_lshrrev + v_and_or_b32
}

// relu -> exp2 -> RNE pack 8 f32 to bf16x8 (element e = k-slot q*8+e)
static __device__ __forceinline__ bf16x8 relu_exp2_pack(f32x4 lo, f32x4 hi) {
  u32x4 t;
  t[0] = pk_rne(fexp2(fmaxf(lo[0], 0.f)), fexp2(fmaxf(lo[1], 0.f)));
  t[1] = pk_rne(fexp2(fmaxf(lo[2], 0.f)), fexp2(fmaxf(lo[3], 0.f)));
  t[2] = pk_rne(fexp2(fmaxf(hi[0], 0.f)), fexp2(fmaxf(hi[1], 0.f)));
  t[3] = pk_rne(fexp2(fmaxf(hi[2], 0.f)), fexp2(fmaxf(hi[3], 0.f)));
  return __builtin_bit_cast(bf16x8, t);
}

// ---- fused: core = tv.k ; t1 = (nv1@core)*log2e (bf16) ; nv2 -> bf16 ; sums=0
__global__ __launch_bounds__(256) void k_prep(const float* __restrict__ nv1,
                                              const float* __restrict__ nv2,
                                              const float* __restrict__ timevec,
                                              const float* __restrict__ kk,
                                              const int* __restrict__ tind,
                                              unsigned short* __restrict__ t1b,
                                              unsigned short* __restrict__ nv2b,
                                              float* __restrict__ sums) {
  __shared__ float cs[1024];
  const int tid = threadIdx.x;
  if (tid < 128) sums[blockIdx.x * 128 + tid] = 0.f;
  const float* tv = timevec + (size_t)tind[0] * DD;
  for (int idx = tid; idx < 1024; idx += 256) {
    float acc = 0.f;
#pragma unroll
    for (int d = 0; d < DD; ++d) acc += tv[d] * kk[d * 1024 + idx];
    cs[idx] = acc;
  }
  __syncthreads();
  const int nbase = blockIdx.x * 128;
  const int f = tid & 31, sub = tid >> 5;
#pragma unroll 4
  for (int it = 0; it < 16; ++it) {
    const int n = nbase + it * 8 + sub;
    const float* nr = nv1 + (size_t)n * DD;
    float acc = 0.f;
#pragma unroll
    for (int e = 0; e < DD; ++e) acc += nr[e] * cs[e * DD + f];
    t1b[(size_t)n * DD + f] = f2bf(acc * 1.4426950408889634f);  // fold log2(e)
  }
#pragma unroll 4
  for (int it = 0; it < 16; ++it) {
    const int idx = nbase * DD + it * 256 + tid;
    nv2b[idx] = f2bf(nv2[idx]);
  }
}

// ---- sums[n] += sum_m exp2(relu(t1[n].nv2[m]))  grid (128 n, 8 m-chunks) ----
__global__ __launch_bounds__(256) void k_stats(const unsigned short* __restrict__ t1b,
                                               const unsigned short* __restrict__ nv2b,
                                               float* __restrict__ sums) {
  const int tid = threadIdx.x;
  const int w = tid >> 6, lane = tid & 63, q = lane >> 4, i16 = lane & 15;
  const int nbase = blockIdx.x * 64 + w * 16;
  bf16x8 a = *(const bf16x8*)(t1b + (size_t)(nbase + i16) * DD + q * 8);
  const f32x4 z4 = {0.f, 0.f, 0.f, 0.f};
  float s[4] = {0.f, 0.f, 0.f, 0.f};
  const int m0 = blockIdx.y * 1024;
  for (int mt = m0; mt < m0 + 1024; mt += 64) {
#pragma unroll
    for (int u = 0; u < 4; ++u) {
      bf16x8 b = *(const bf16x8*)(nv2b + (size_t)(mt + u * 16 + i16) * DD + q * 8);
      f32x4 d = __builtin_amdgcn_mfma_f32_16x16x32_bf16(a, b, z4, 0, 0, 0);
#pragma unroll
      for (int r = 0; r < 4; ++r) s[r] += fexp2(fmaxf(d[r], 0.f));
    }
  }
#pragma unroll
  for (int r = 0; r < 4; ++r)
    for (int off = 1; off < 16; off <<= 1) s[r] += __shfl_xor(s[r], off, 64);
  if (i16 == 0) {
#pragma unroll
    for (int r = 0; r < 4; ++r) atomicAdd(&sums[nbase + q * 4 + r], s[r]);
  }
}

// ---- yT[col][n] = bf16(x[bc][n][t] / sums[n]) via LDS transpose (pad 12->13) ----
__global__ __launch_bounds__(256) void k_y(const float* __restrict__ x,
                                           const float* __restrict__ sums,
                                           unsigned short* __restrict__ yT) {
  __shared__ float xs[3328];  // 256 * 13
  const int tid = threadIdx.x;
  const int n0 = blockIdx.x * 256;
  const int bc = blockIdx.y;
  const float* xp = x + (size_t)bc * NN * TT + (size_t)n0 * TT;
#pragma unroll
  for (int j = 0; j < 12; ++j) {
    const int idx = j * 256 + tid;
    xs[(idx / 12) * 13 + idx % 12] = xp[idx];
  }
  __syncthreads();
  const float rinv = 1.0f / sums[n0 + tid];
#pragma unroll
  for (int t = 0; t < 12; ++t)
    yT[(size_t)(bc * TT + t) * NN + n0 + tid] = f2bf(xs[tid * 13 + t] * rinv);
}

// ---- k_mega: part[nc][col][m] = sum_{n in chunk} E[n][m] * y[col][n] ----
// grid (128 m-blocks of 64, 8 chunks of 1024 n); 256 thr = 4 waves.
// Pipelined barrier-free: at iter sl, gen slice sl's E logits while the
// 12 acc MFMAs consume slice sl-1's packed E and y. Grouped 2+2 m-strips
// to bound the f32x4 transient at 16 VGPRs. No LDS, no __syncthreads.
__global__ __launch_bounds__(256, 3) void k_mega(const unsigned short* __restrict__ t1b,
                                                 const unsigned short* __restrict__ nv2b,
                                                 const unsigned short* __restrict__ yT,
                                                 float* __restrict__ part) {
  const int tid = threadIdx.x;
  const int w = tid >> 6, lane = tid & 63, q = lane >> 4, i16 = lane & 15;
  const int mb = blockIdx.x * 64;
  const int nt0 = blockIdx.y * CHUNK;

  // gen B-frags (loop-invariant): bg[ms][k=d] at col m = mb+ms*16+i16
  bf16x8 bg[4];
#pragma unroll
  for (int ms = 0; ms < 4; ++ms)
    bg[ms] = *(const bf16x8*)(nv2b + (size_t)(mb + ms * 16 + i16) * DD + q * 8);

  f32x4 acc[3][4];
#pragma unroll
  for (int c = 0; c < 3; ++c)
#pragma unroll
    for (int ms = 0; ms < 4; ++ms) acc[c][ms] = (f32x4){0.f, 0.f, 0.f, 0.f};

  // gen A-frag row permutation (HW-verified R13): A-row i16 <- t1 row
  // nt + 8*(i16>>2)+(i16&3), +4 for phase B.
  const int perm = ((i16 >> 2) << 3) | (i16 & 3);
  const unsigned short* tp = t1b + (size_t)(nt0 + perm) * DD + q * 8;
  // acc A-frags: y[col = (w*3+c)*16 + i16][n = nt + q*8 + e]
  const unsigned short* yp0 = yT + (size_t)((w * 3 + 0) * 16 + i16) * NN + nt0 + q * 8;
  const unsigned short* yp1 = yp0 + (size_t)16 * NN;
  const unsigned short* yp2 = yp1 + (size_t)16 * NN;

  const f32x4 z4 = {0.f, 0.f, 0.f, 0.f};

  // ---- prologue: e = E[0], y = y[0], alo/ahi = t1[1] ----
  bf16x8 alo = *(const bf16x8*)tp;
  bf16x8 ahi = *(const bf16x8*)(tp + 4 * DD);
  bf16x8 e[4];
#pragma unroll
  for (int ms = 0; ms < 4; ++ms) {
    f32x4 dlo = MFMA32(alo, bg[ms], z4);
    f32x4 dhi = MFMA32(ahi, bg[ms], z4);
    e[ms] = relu_exp2_pack(dlo, dhi);
  }
  bf16x8 y0 = *(const bf16x8*)yp0;
  bf16x8 y1 = *(const bf16x8*)yp1;
  bf16x8 y2 = *(const bf16x8*)yp2;
  alo = *(const bf16x8*)(tp + 32 * DD);
  ahi = *(const bf16x8*)(tp + 36 * DD);

  for (int sl = 1; sl < 32; ++sl) {
    // loads: y[sl] and t1[sl+1]. t1 prefetch at sl=31 reads one tile past
    // the chunk (lands in nv2b region of the workspace; never consumed).
    const int o = sl * 32;
    bf16x8 y0n = *(const bf16x8*)(yp0 + o);
    bf16x8 y1n = *(const bf16x8*)(yp1 + o);
    bf16x8 y2n = *(const bf16x8*)(yp2 + o);
    bf16x8 alo_n = *(const bf16x8*)(tp + (size_t)(o + 32) * DD);
    bf16x8 ahi_n = *(const bf16x8*)(tp + (size_t)(o + 36) * DD);

    // ---- group A: gen ms 0,1 of slice sl; acc ms 0,1 of slice sl-1 ----
    f32x4 d00 = MFMA32(alo, bg[0], z4);
    f32x4 d01 = MFMA32(ahi, bg[0], z4);
    f32x4 d10 = MFMA32(alo, bg[1], z4);
    f32x4 d11 = MFMA32(ahi, bg[1], z4);
    acc[0][0] = MFMA32(y0, e[0], acc[0][0]);
    acc[1][0] = MFMA32(y1, e[0], acc[1][0]);
    acc[2][0] = MFMA32(y2, e[0], acc[2][0]);
    acc[0][1] = MFMA32(y0, e[1], acc[0][1]);
    acc[1][1] = MFMA32(y1, e[1], acc[1][1]);
    acc[2][1] = MFMA32(y2, e[1], acc[2][1]);
    e[0] = relu_exp2_pack(d00, d01);
    e[1] = relu_exp2_pack(d10, d11);

    // ---- group B: gen ms 2,3 of slice sl; acc ms 2,3 of slice sl-1 ----
    f32x4 d20 = MFMA32(alo, bg[2], z4);
    f32x4 d21 = MFMA32(ahi, bg[2], z4);
    f32x4 d30 = MFMA32(alo, bg[3], z4);
    f32x4 d31 = MFMA32(ahi, bg[3], z4);
    acc[0][2] = MFMA32(y0, e[2], acc[0][2]);
    acc[1][2] = MFMA32(y1, e[2], acc[1][2]);
    acc[2][2] = MFMA32(y2, e[2], acc[2][2]);
    acc[0][3] = MFMA32(y0, e[3], acc[0][3]);
    acc[1][3] = MFMA32(y1, e[3], acc[1][3]);
    acc[2][3] = MFMA32(y2, e[3], acc[2][3]);
    e[2] = relu_exp2_pack(d20, d21);
    e[3] = relu_exp2_pack(d30, d31);

    y0 = y0n; y1 = y1n; y2 = y2n;
    alo = alo_n; ahi = ahi_n;
  }

  // ---- epilogue: acc slice 31 ----
#pragma unroll
  for (int ms = 0; ms < 4; ++ms) {
    acc[0][ms] = MFMA32(y0, e[ms], acc[0][ms]);
    acc[1][ms] = MFMA32(y1, e[ms], acc[1][ms]);
    acc[2][ms] = MFMA32(y2, e[ms], acc[2][ms]);
  }

  // epilogue: lane holds col = (w*3+c)*16 + q*4 + r, m = mb + ms*16 + i16
  float* pp = part + (size_t)blockIdx.y * 192 * NN;
#pragma unroll
  for (int c = 0; c < 3; ++c)
#pragma unroll
    for (int ms = 0; ms < 4; ++ms) {
      const int colbase = (w * 3 + c) * 16 + q * 4;
      const int m = mb + ms * 16 + i16;
#pragma unroll
      for (int r = 0; r < 4; ++r)
        pp[(size_t)(colbase + r) * NN + m] = acc[c][ms][r];
    }
}

// ---- reduce NSPLIT partials + transpose to out[bc][m][t] (pad 12->13) ----
__global__ __launch_bounds__(256) void k_reduce(const float* __restrict__ part,
                                                float* __restrict__ out) {
  __shared__ float os[3328];  // 256 * 13
  const int tid = threadIdx.x;
  const int m0 = blockIdx.x * 256;
  const int bc = blockIdx.y;
#pragma unroll
  for (int t = 0; t < 12; ++t) {
    const int col = bc * TT + t;
    float s = 0.f;
#pragma unroll
    for (int nc = 0; nc < NSPLIT; ++nc)
      s += part[((size_t)nc * 192 + col) * NN + m0 + tid];
    os[tid * 13 + t] = s;
  }
  __syncthreads();
  float* op = out + (size_t)bc * NN * TT + (size_t)m0 * TT;
#pragma unroll
  for (int j = 0; j < 12; ++j) {
    const int idx = j * 256 + tid;
    op[idx] = os[(idx / 12) * 13 + idx % 12];
  }
}

extern "C" void kernel_launch(void* const* d_in, const int* in_sizes, int n_in,
                              void* d_out, int out_size, void* d_ws, size_t ws_size,
                              hipStream_t stream) {
  const float* x = (const float*)d_in[0];
  const float* nv1 = (const float*)d_in[1];
  const float* nv2 = (const float*)d_in[2];
  const float* tv = (const float*)d_in[3];
  const float* kk = (const float*)d_in[4];
  const int* tind = (const int*)d_in[5];
  float* out = (float*)d_out;

  char* ws = (char*)d_ws;
  unsigned short* t1b  = (unsigned short*)(ws);            //  524288 B
  unsigned short* nv2b = (unsigned short*)(ws + 524288);   //  524288 B
  float* sums          = (float*)(ws + 1048576);           //   32768 B
  unsigned short* yT   = (unsigned short*)(ws + 1081344);  // 3145728 B -> 4227072
  float* part          = (float*)(ws + 4227072);           // 50331648 B -> 54558720

  k_prep<<<64, 256, 0, stream>>>(nv1, nv2, tv, kk, tind, t1b, nv2b, sums);
  k_stats<<<dim3(128, 8), 256, 0, stream>>>(t1b, nv2b, sums);
  k_y<<<dim3(32, 16), 256, 0, stream>>>(x, sums, yT);
  k_mega<<<dim3(128, NSPLIT), 256, 0, stream>>>(t1b, nv2b, yT, part);
  k_reduce<<<dim3(32, 16), 256, 0, stream>>>(part, out);
}